// Round 5
// baseline (124.114 us; speedup 1.0000x reference)
//
#include <hip/hip_runtime.h>
#include <math.h>

#define NIMG 64
#define HW   1024
#define NCH  85
#define NCLS 80
#define CONF_TH 0.25f
#define NMS_TH  0.35f

__device__ __forceinline__ float fast_tanh(float x) {
  float e = __expf(2.0f * x);
  return 1.0f - 2.0f * __builtin_amdgcn_rcpf(e + 1.0f);
}
__device__ __forceinline__ float fast_sigmoid(float x) {
  return __builtin_amdgcn_rcpf(1.0f + __expf(-x));
}

// ---------------------------------------------------------------------------
// Single fused kernel: 256 blocks x 256 threads.
// Decode: IDENTICAL thread->pixel mapping and math to the proven round-1
// decode (gid = blockIdx*256+tid; fully-coalesced; 4 independent 20-class
// argmax chains; ascending merge with strict '>' == first-occurrence argmax).
// Then last-block election per image (threadfence + device-scope atomicAdd,
// counters pre-zeroed via hipMemsetAsync): the 4th finisher acquires and runs
// the proven 256-thread NMS ladder (round-2 body, full 80 classes, verified
// correct) for its image. Saves one kernel launch + overlaps NMS with decode.
// ---------------------------------------------------------------------------
__global__ __launch_bounds__(256) void fused_kernel(const float* __restrict__ preds,
                                                    float* __restrict__ out,
                                                    float* __restrict__ keepOut,
                                                    int* __restrict__ counters) {
  int tid = threadIdx.x;
  int gid = blockIdx.x * 256 + tid;   // 0 .. 65535  (same mapping as round-1)
  int n = gid >> 10;
  int t = gid & 1023;
  const float* bp = preds + (size_t)n * (NCH * HW) + t;

  // ---- decode (verbatim round-1) ----
  float pobj = bp[0];
  float tx = bp[(size_t)1 * HW];
  float ty = bp[(size_t)2 * HW];
  float tw = bp[(size_t)3 * HW];
  float th = bp[(size_t)4 * HW];

  float b0, b1, b2, b3;
  int i0, i1, i2, i3;
  b0 = bp[(size_t)(5 +  0) * HW]; i0 =  0;
  b1 = bp[(size_t)(5 + 20) * HW]; i1 = 20;
  b2 = bp[(size_t)(5 + 40) * HW]; i2 = 40;
  b3 = bp[(size_t)(5 + 60) * HW]; i3 = 60;
#pragma unroll
  for (int c = 1; c < 20; ++c) {
    float v0 = bp[(size_t)(5 +  0 + c) * HW];
    float v1 = bp[(size_t)(5 + 20 + c) * HW];
    float v2 = bp[(size_t)(5 + 40 + c) * HW];
    float v3 = bp[(size_t)(5 + 60 + c) * HW];
    if (v0 > b0) { b0 = v0; i0 =  0 + c; }
    if (v1 > b1) { b1 = v1; i1 = 20 + c; }
    if (v2 > b2) { b2 = v2; i2 = 40 + c; }
    if (v3 > b3) { b3 = v3; i3 = 60 + c; }
  }
  float best = b0; int bc = i0;
  if (b1 > best) { best = b1; bc = i1; }
  if (b2 > best) { best = b2; bc = i2; }
  if (b3 > best) { best = b3; bc = i3; }

  float score = pobj * best;                 // bit-exact vs reference

  float gx = (float)(t & 31);
  float gy = (float)(t >> 5);
  float bcx = (fast_tanh(tx) + gx) * 0.03125f;
  float bcy = (fast_tanh(ty) + gy) * 0.03125f;
  float bw = fast_sigmoid(tw);
  float bh = fast_sigmoid(th);

  float x1 = bcx - 0.5f * bw, y1 = bcy - 0.5f * bh;
  float x2 = bcx + 0.5f * bw, y2 = bcy + 0.5f * bh;

  float2* ob = (float2*)(out + (size_t)gid * 6);
  ob[0] = make_float2(x1, y1);
  ob[1] = make_float2(x2, y2);
  ob[2] = make_float2(score, (float)bc);

  keepOut[gid] = 0.0f;

  // ---- last-block election for image n (release -> count -> acquire) ----
  __shared__ int amLast;
  __threadfence();                       // release this thread's global stores
  __syncthreads();                       // all block stores issued+fenced
  if (tid == 0) amLast = (atomicAdd(&counters[n], 1) == 3);  // device-scope
  __syncthreads();
  if (!amLast) return;                   // uniform: 3 of 4 blocks exit
  __threadfence();                       // acquire before reading remote boxes

  // ---- NMS ladder (proven round-2 body, full 80 classes, 4 boxes/thread) --
  __shared__ float sx1[HW], sy1[HW], sx2[HW], sy2[HW], sarea[HW], sscore[HW];
  __shared__ int bucket[HW];                 // unordered class members
  __shared__ int sorted[HW];                 // (score desc, idx asc) order
  __shared__ unsigned long long supp[HW];    // suppression bits vs lower ranks
  __shared__ int cnt[NCLS], offs[NCLS], start[NCLS];

  if (tid < NCLS) cnt[tid] = 0;

  float px1[4], py1[4], px2[4], py2[4], par[4], psc[4];
  int pcl[4]; bool pval[4];
#pragma unroll
  for (int k = 0; k < 4; ++k) {
    int p = tid + 256 * k;
    const float2* ib = (const float2*)(out + ((size_t)n * HW + p) * 6);
    float2 a01 = ib[0];
    float2 a23 = ib[1];
    float2 a45 = ib[2];
    px1[k] = a01.x; py1[k] = a01.y; px2[k] = a23.x; py2[k] = a23.y;
    psc[k] = a45.x;
    pcl[k] = (int)a45.y;
    par[k] = (px2[k] - px1[k]) * (py2[k] - py1[k]);
    sx1[p] = px1[k]; sy1[p] = py1[k]; sx2[p] = px2[k]; sy2[p] = py2[k];
    sarea[p] = par[k];
    sscore[p] = psc[k];
    pval[k] = psc[k] > CONF_TH;
  }
  __syncthreads();

  // ---- count valid per class ----
#pragma unroll
  for (int k = 0; k < 4; ++k)
    if (pval[k]) atomicAdd(&cnt[pcl[k]], 1);
  __syncthreads();

  // ---- exclusive prefix sum over 80 class counts (wave-0 paired scan) ----
  if (tid < 64) {
    int c0 = (2 * tid < NCLS) ? cnt[2 * tid] : 0;
    int c1 = (2 * tid + 1 < NCLS) ? cnt[2 * tid + 1] : 0;
    int ps = c0 + c1;
    int x = ps;
#pragma unroll
    for (int d = 1; d < 64; d <<= 1) {
      int y = __shfl_up(x, d, 64);
      if (tid >= d) x += y;
    }
    int excl = x - ps;
    if (2 * tid < NCLS)     { start[2 * tid] = excl;          offs[2 * tid] = excl; }
    if (2 * tid + 1 < NCLS) { start[2 * tid + 1] = excl + c0; offs[2 * tid + 1] = excl + c0; }
  }
  __syncthreads();

  // ---- scatter valid boxes to class buckets (order irrelevant) ----
#pragma unroll
  for (int k = 0; k < 4; ++k)
    if (pval[k]) {
      int p = atomicAdd(&offs[pcl[k]], 1);
      bucket[p] = tid + 256 * k;
    }
  __syncthreads();

  // ---- parallel rank within class = exact stable-argsort position ----
  int rk[4];
#pragma unroll
  for (int k = 0; k < 4; ++k)
    if (pval[k]) {
      int p = tid + 256 * k;
      int cl = pcl[k];
      int s0 = start[cl], m = cnt[cl];
      float sc = psc[k];
      int r = 0;
      for (int j = 0; j < m; ++j) {
        int jb = bucket[s0 + j];
        float sj = sscore[jb];
        r += (sj > sc) || (sj == sc && jb < p);
      }
      rk[k] = r;
      sorted[s0 + r] = p;
    }
  __syncthreads();

  // ---- parallel suppression bitmasks vs all lower-rank members ----
#pragma unroll
  for (int k = 0; k < 4; ++k)
    if (pval[k]) {
      int cl = pcl[k];
      int s0 = start[cl];
      int a = rk[k];
      int lim = a < 64 ? a : 64;
      unsigned long long mask = 0ull;
      for (int b = 0; b < lim; ++b) {
        int jb = sorted[s0 + b];
        float iw = fminf(px2[k], sx2[jb]) - fmaxf(px1[k], sx1[jb]);
        float ih = fminf(py2[k], sy2[jb]) - fmaxf(py1[k], sy1[jb]);
        iw = fmaxf(iw, 0.0f);
        ih = fmaxf(ih, 0.0f);
        float inter = iw * ih;
        float iou = inter / (par[k] + sarea[jb] - inter + 1e-9f);  // exact ref op order
        if (iou > NMS_TH) mask |= (1ull << b);
      }
      supp[s0 + a] = mask;
    }
  __syncthreads();

  // ---- serial greedy scan per class: O(m) register bit-ops ----
  if (tid < NCLS) {
    int m = cnt[tid], s0 = start[tid];
    if (m <= 64) {
      unsigned long long kept = 0ull;
      for (int a = 0; a < m; ++a) {
        unsigned long long sa = supp[s0 + a];
        if ((sa & kept) == 0ull) {
          kept |= (1ull << a);
          keepOut[(size_t)n * HW + sorted[s0 + a]] = 1.0f;
        }
      }
    } else {
      // never expected (Poisson mean ~6/class); exact O(m^2) fallback
      for (int a = 0; a < m; ++a) {
        int ia = sorted[s0 + a];
        float ax1 = sx1[ia], ay1 = sy1[ia], ax2 = sx2[ia], ay2 = sy2[ia];
        float ar2 = sarea[ia];
        bool kp = true;
        for (int b = 0; b < a; ++b) {
          if (!bucket[s0 + b]) continue;   // bucket reused as kept-flags
          int jb = sorted[s0 + b];
          float iw = fminf(ax2, sx2[jb]) - fmaxf(ax1, sx1[jb]);
          float ih = fminf(ay2, sy2[jb]) - fmaxf(ay1, sy1[jb]);
          iw = fmaxf(iw, 0.0f);
          ih = fmaxf(ih, 0.0f);
          float inter = iw * ih;
          float iou = inter / (ar2 + sarea[jb] - inter + 1e-9f);
          if (iou > NMS_TH) { kp = false; break; }
        }
        bucket[s0 + a] = kp ? 1 : 0;
        if (kp) keepOut[(size_t)n * HW + ia] = 1.0f;
      }
    }
  }
}

// ---------------------------------------------------------------------------
// Fallback path (workspace too small for counters): proven round-1 two-kernel
// structure, 73.8us. Kept verbatim for safety.
// ---------------------------------------------------------------------------
__global__ __launch_bounds__(256) void decode_kernel(const float* __restrict__ preds,
                                                     float* __restrict__ out,
                                                     float* __restrict__ keepOut) {
  int gid = blockIdx.x * 256 + threadIdx.x;
  int n = gid >> 10;
  int t = gid & 1023;
  const float* bp = preds + (size_t)n * (NCH * HW) + t;

  float pobj = bp[0];
  float tx = bp[(size_t)1 * HW];
  float ty = bp[(size_t)2 * HW];
  float tw = bp[(size_t)3 * HW];
  float th = bp[(size_t)4 * HW];

  float b0, b1, b2, b3;
  int i0, i1, i2, i3;
  b0 = bp[(size_t)(5 +  0) * HW]; i0 =  0;
  b1 = bp[(size_t)(5 + 20) * HW]; i1 = 20;
  b2 = bp[(size_t)(5 + 40) * HW]; i2 = 40;
  b3 = bp[(size_t)(5 + 60) * HW]; i3 = 60;
#pragma unroll
  for (int c = 1; c < 20; ++c) {
    float v0 = bp[(size_t)(5 +  0 + c) * HW];
    float v1 = bp[(size_t)(5 + 20 + c) * HW];
    float v2 = bp[(size_t)(5 + 40 + c) * HW];
    float v3 = bp[(size_t)(5 + 60 + c) * HW];
    if (v0 > b0) { b0 = v0; i0 =  0 + c; }
    if (v1 > b1) { b1 = v1; i1 = 20 + c; }
    if (v2 > b2) { b2 = v2; i2 = 40 + c; }
    if (v3 > b3) { b3 = v3; i3 = 60 + c; }
  }
  float best = b0; int bc = i0;
  if (b1 > best) { best = b1; bc = i1; }
  if (b2 > best) { best = b2; bc = i2; }
  if (b3 > best) { best = b3; bc = i3; }

  float score = pobj * best;

  float gx = (float)(t & 31);
  float gy = (float)(t >> 5);
  float bcx = (fast_tanh(tx) + gx) * 0.03125f;
  float bcy = (fast_tanh(ty) + gy) * 0.03125f;
  float bw = fast_sigmoid(tw);
  float bh = fast_sigmoid(th);

  float x1 = bcx - 0.5f * bw, y1 = bcy - 0.5f * bh;
  float x2 = bcx + 0.5f * bw, y2 = bcy + 0.5f * bh;

  float2* ob = (float2*)(out + (size_t)gid * 6);
  ob[0] = make_float2(x1, y1);
  ob[1] = make_float2(x2, y2);
  ob[2] = make_float2(score, (float)bc);

  keepOut[gid] = 0.0f;
}

__global__ __launch_bounds__(1024) void nms_kernel(const float* __restrict__ boxes,
                                                   float* __restrict__ keepOut) {
  int n = blockIdx.x;
  int t = threadIdx.x;

  __shared__ float sx1[HW], sy1[HW], sx2[HW], sy2[HW], sarea[HW], sscore[HW];
  __shared__ int bucket[HW];
  __shared__ int sorted[HW];
  __shared__ int srank[HW];
  __shared__ unsigned long long supp[HW];
  __shared__ int cnt[NCLS], offs[NCLS], start[NCLS];

  if (t < NCLS) cnt[t] = 0;

  size_t gb = (size_t)n * HW + t;
  const float2* ib = (const float2*)(boxes + gb * 6);
  float2 a01 = ib[0];
  float2 a23 = ib[1];
  float2 a45 = ib[2];
  float x1 = a01.x, y1 = a01.y, x2 = a23.x, y2 = a23.y;
  float score = a45.x;
  int bc = (int)a45.y;

  float aar = (x2 - x1) * (y2 - y1);
  sx1[t] = x1; sy1[t] = y1; sx2[t] = x2; sy2[t] = y2;
  sarea[t] = aar;
  sscore[t] = score;
  bool valid = score > CONF_TH;
  __syncthreads();

  if (valid) atomicAdd(&cnt[bc], 1);
  __syncthreads();

  if (t < 64) {
    int c0 = (2 * t < NCLS) ? cnt[2 * t] : 0;
    int c1 = (2 * t + 1 < NCLS) ? cnt[2 * t + 1] : 0;
    int ps = c0 + c1;
    int x = ps;
#pragma unroll
    for (int d = 1; d < 64; d <<= 1) {
      int y = __shfl_up(x, d, 64);
      if (t >= d) x += y;
    }
    int excl = x - ps;
    if (2 * t < NCLS)     { start[2 * t] = excl;          offs[2 * t] = excl; }
    if (2 * t + 1 < NCLS) { start[2 * t + 1] = excl + c0; offs[2 * t + 1] = excl + c0; }
  }
  __syncthreads();

  if (valid) {
    int p = atomicAdd(&offs[bc], 1);
    bucket[p] = t;
  }
  __syncthreads();

  if (valid) {
    int s0 = start[bc], m = cnt[bc];
    int r = 0;
    for (int j = 0; j < m; ++j) {
      int jb = bucket[s0 + j];
      float sj = sscore[jb];
      r += (sj > score) || (sj == score && jb < t);
    }
    srank[t] = r;
    sorted[s0 + r] = t;
  }
  __syncthreads();

  if (valid) {
    int s0 = start[bc];
    int a = srank[t];
    int lim = a < 64 ? a : 64;
    unsigned long long mask = 0ull;
    for (int b = 0; b < lim; ++b) {
      int jb = sorted[s0 + b];
      float iw = fminf(x2, sx2[jb]) - fmaxf(x1, sx1[jb]);
      float ih = fminf(y2, sy2[jb]) - fmaxf(y1, sy1[jb]);
      iw = fmaxf(iw, 0.0f);
      ih = fmaxf(ih, 0.0f);
      float inter = iw * ih;
      float iou = inter / (aar + sarea[jb] - inter + 1e-9f);
      if (iou > NMS_TH) mask |= (1ull << b);
    }
    supp[s0 + a] = mask;
  }
  __syncthreads();

  if (t < NCLS) {
    int m = cnt[t], s0 = start[t];
    if (m <= 64) {
      unsigned long long kept = 0ull;
      for (int a = 0; a < m; ++a) {
        unsigned long long sa = supp[s0 + a];
        if ((sa & kept) == 0ull) {
          kept |= (1ull << a);
          keepOut[(size_t)n * HW + sorted[s0 + a]] = 1.0f;
        }
      }
    } else {
      for (int a = 0; a < m; ++a) {
        int ia = sorted[s0 + a];
        float ax1 = sx1[ia], ay1 = sy1[ia], ax2 = sx2[ia], ay2 = sy2[ia];
        float ar2 = sarea[ia];
        bool kp = true;
        for (int b = 0; b < a; ++b) {
          if (!bucket[s0 + b]) continue;
          int jb = sorted[s0 + b];
          float iw = fminf(ax2, sx2[jb]) - fmaxf(ax1, sx1[jb]);
          float ih = fminf(ay2, sy2[jb]) - fmaxf(ay1, sy1[jb]);
          iw = fmaxf(iw, 0.0f);
          ih = fmaxf(ih, 0.0f);
          float inter = iw * ih;
          float iou = inter / (ar2 + sarea[jb] - inter + 1e-9f);
          if (iou > NMS_TH) { kp = false; break; }
        }
        bucket[s0 + a] = kp ? 1 : 0;
        if (kp) keepOut[(size_t)n * HW + ia] = 1.0f;
      }
    }
  }
}

extern "C" void kernel_launch(void* const* d_in, const int* in_sizes, int n_in,
                              void* d_out, int out_size, void* d_ws, size_t ws_size,
                              hipStream_t stream) {
  const float* preds = (const float*)d_in[0];
  float* out = (float*)d_out;
  float* keepOut = out + (size_t)NIMG * HW * 6;

  if (d_ws != nullptr && ws_size >= NIMG * sizeof(int)) {
    hipMemsetAsync(d_ws, 0, NIMG * sizeof(int), stream);
    fused_kernel<<<NIMG * HW / 256, 256, 0, stream>>>(preds, out, keepOut, (int*)d_ws);
  } else {
    decode_kernel<<<NIMG * HW / 256, 256, 0, stream>>>(preds, out, keepOut);
    nms_kernel<<<NIMG, HW, 0, stream>>>(out, keepOut);
  }
}

// Round 6
// 75.358 us; speedup vs baseline: 1.6470x; 1.6470x over previous
//
#include <hip/hip_runtime.h>
#include <math.h>

#define NIMG 64
#define HW   1024
#define NCH  85
#define NCLS 80
#define CONF_TH 0.25f
#define NMS_TH  0.35f

__device__ __forceinline__ float fast_tanh(float x) {
  float e = __expf(2.0f * x);
  return 1.0f - 2.0f * __builtin_amdgcn_rcpf(e + 1.0f);
}
__device__ __forceinline__ float fast_sigmoid(float x) {
  return __builtin_amdgcn_rcpf(1.0f + __expf(-x));
}

// Partial argmax over NC class channels starting at absolute channel CL0,
// for 4 consecutive pixels (float4 lanes). Ascending channel order + strict >
// == exact first-occurrence argmax within the quarter.
template <int CL0, int NC>
__device__ __forceinline__ void quarter_argmax(const float* __restrict__ bp,
                                               float4& mv, int4& mi) {
  float4 v = *(const float4*)(bp + (size_t)CL0 * HW);
  float b0 = v.x, b1 = v.y, b2 = v.z, b3 = v.w;
  int i0 = CL0 - 5, i1 = i0, i2 = i0, i3 = i0;
#pragma unroll
  for (int c = 1; c < NC; ++c) {
    float4 u = *(const float4*)(bp + (size_t)(CL0 + c) * HW);
    int ci = CL0 - 5 + c;
    if (u.x > b0) { b0 = u.x; i0 = ci; }
    if (u.y > b1) { b1 = u.y; i1 = ci; }
    if (u.z > b2) { b2 = u.z; i2 = ci; }
    if (u.w > b3) { b3 = u.w; i3 = ci; }
  }
  mv = make_float4(b0, b1, b2, b3);
  mi = make_int4(i0, i1, i2, i3);
}

// ---------------------------------------------------------------------------
// Fused decode + class-aware NMS. One block per image, 1024 threads.
// Decode: float4 loads (1 KB/wave-instr), channel space split across 4
// wave-uniform thread quarters; partials combined per-pixel via LDS.
// NMS: parallel rank + parallel suppression bitmasks + O(m) serial bit-scan.
// ---------------------------------------------------------------------------
__global__ __launch_bounds__(1024) void fused_kernel(const float* __restrict__ preds,
                                                     float* __restrict__ out,
                                                     float* __restrict__ keepOut) {
  int n = blockIdx.x;
  int t = threadIdx.x;
  int q  = t >> 8;          // channel quarter (wave-uniform)
  int pg = t & 255;         // pixel group: pixels 4*pg .. 4*pg+3

  __shared__ float sx1[HW], sy1[HW], sx2[HW], sy2[HW], sarea[HW], sscore[HW];
  __shared__ int scls[HW];
  __shared__ int bucket[HW];                 // unordered class members
  __shared__ int sorted[HW];                 // (score desc, idx asc) order
  __shared__ int srank[HW];
  __shared__ unsigned long long supp[HW];    // suppression bits vs lower ranks
  __shared__ int cnt[NCLS], offs[NCLS], start[NCLS];
  __shared__ float pmaxv[4][HW];             // per-quarter partial max  [q][pixel]
  __shared__ int   pmaxi[4][HW];             // per-quarter partial argmax
  __shared__ float sobj[HW];
  __shared__ float sreg[4][HW];              // tx, ty, tw, th

  if (t < NCLS) cnt[t] = 0;

  // ---- decode phase A: cooperative float4 channel loads ----
  const float* bp = preds + (size_t)n * (NCH * HW) + 4 * pg;
  float4 mv; int4 mi;
  if (q == 0) {
    float4 vobj = *(const float4*)(bp);
    ((float4*)sobj)[pg] = vobj;
#pragma unroll
    for (int r = 0; r < 4; ++r) {
      float4 vr = *(const float4*)(bp + (size_t)(1 + r) * HW);
      ((float4*)&sreg[r][0])[pg] = vr;
    }
    quarter_argmax<5, 16>(bp, mv, mi);     // classes  0..15
  } else if (q == 1) {
    quarter_argmax<21, 21>(bp, mv, mi);    // classes 16..36
  } else if (q == 2) {
    quarter_argmax<42, 21>(bp, mv, mi);    // classes 37..57
  } else {
    quarter_argmax<63, 22>(bp, mv, mi);    // classes 58..79
  }
  ((float4*)&pmaxv[q][0])[pg] = mv;
  ((int4*)&pmaxi[q][0])[pg] = mi;
  __syncthreads();

  // ---- decode phase B: per-pixel combine (ascending q, strict > ==
  //      exact first-occurrence across quarters) + box math ----
  float pobj = sobj[t];
  float tx = sreg[0][t], ty = sreg[1][t], tw = sreg[2][t], th = sreg[3][t];
  float best = pmaxv[0][t]; int bc = pmaxi[0][t];
#pragma unroll
  for (int qq = 1; qq < 4; ++qq) {
    float v = pmaxv[qq][t];
    if (v > best) { best = v; bc = pmaxi[qq][t]; }
  }
  float score = pobj * best;               // bit-exact vs reference

  float gx = (float)(t & 31);
  float gy = (float)(t >> 5);
  float bcx = (fast_tanh(tx) + gx) * 0.03125f;
  float bcy = (fast_tanh(ty) + gy) * 0.03125f;
  float bw = fast_sigmoid(tw);
  float bh = fast_sigmoid(th);

  float x1 = bcx - 0.5f * bw, y1 = bcy - 0.5f * bh;
  float x2 = bcx + 0.5f * bw, y2 = bcy + 0.5f * bh;

  size_t gb = (size_t)n * HW + t;
  float2* ob = (float2*)(out + gb * 6);    // fire-and-forget output store
  ob[0] = make_float2(x1, y1);
  ob[1] = make_float2(x2, y2);
  ob[2] = make_float2(score, (float)bc);

  sx1[t] = x1; sy1[t] = y1; sx2[t] = x2; sy2[t] = y2;
  float aar = (x2 - x1) * (y2 - y1);
  sarea[t] = aar;
  sscore[t] = score;
  scls[t] = bc;
  bool valid = score > CONF_TH;
  keepOut[gb] = 0.0f;
  __syncthreads();

  // ---- count valid per class ----
  if (valid) atomicAdd(&cnt[bc], 1);
  __syncthreads();

  // ---- exclusive prefix sum over 80 class counts (wave-0 shfl scan) ----
  if (t < 64) {
    int c0 = (2 * t < NCLS) ? cnt[2 * t] : 0;
    int c1 = (2 * t + 1 < NCLS) ? cnt[2 * t + 1] : 0;
    int ps = c0 + c1;
    int x = ps;
#pragma unroll
    for (int d = 1; d < 64; d <<= 1) {
      int y = __shfl_up(x, d, 64);
      if (t >= d) x += y;
    }
    int excl = x - ps;
    if (2 * t < NCLS)     { start[2 * t] = excl;          offs[2 * t] = excl; }
    if (2 * t + 1 < NCLS) { start[2 * t + 1] = excl + c0; offs[2 * t + 1] = excl + c0; }
  }
  __syncthreads();

  // ---- scatter valid boxes to class buckets (order irrelevant) ----
  if (valid) {
    int p = atomicAdd(&offs[bc], 1);
    bucket[p] = t;
  }
  __syncthreads();

  // ---- parallel rank within class = exact stable-argsort position ----
  if (valid) {
    int s0 = start[bc], m = cnt[bc];
    int r = 0;
    for (int j = 0; j < m; ++j) {
      int jb = bucket[s0 + j];
      float sj = sscore[jb];
      r += (sj > score) || (sj == score && jb < t);
    }
    srank[t] = r;
    sorted[s0 + r] = t;
  }
  __syncthreads();

  // ---- parallel suppression bitmasks vs all lower-rank members ----
  if (valid) {
    int s0 = start[bc];
    int a = srank[t];
    int lim = a < 64 ? a : 64;
    unsigned long long mask = 0ull;
    for (int b = 0; b < lim; ++b) {
      int jb = sorted[s0 + b];
      float iw = fminf(x2, sx2[jb]) - fmaxf(x1, sx1[jb]);
      float ih = fminf(y2, sy2[jb]) - fmaxf(y1, sy1[jb]);
      iw = fmaxf(iw, 0.0f);
      ih = fmaxf(ih, 0.0f);
      float inter = iw * ih;
      float iou = inter / (aar + sarea[jb] - inter + 1e-9f);  // exact ref op order
      if (iou > NMS_TH) mask |= (1ull << b);
    }
    supp[s0 + a] = mask;
  }
  __syncthreads();

  // ---- serial greedy scan per class: O(m) register bit-ops ----
  if (t < NCLS) {
    int m = cnt[t], s0 = start[t];
    if (m <= 64) {
      unsigned long long kept = 0ull;
      for (int a = 0; a < m; ++a) {
        unsigned long long sa = supp[s0 + a];
        if ((sa & kept) == 0ull) {
          kept |= (1ull << a);
          keepOut[(size_t)n * HW + sorted[s0 + a]] = 1.0f;
        }
      }
    } else {
      // never expected (Poisson mean ~6/class); exact O(m^2) fallback
      for (int a = 0; a < m; ++a) {
        int ia = sorted[s0 + a];
        float ax1 = sx1[ia], ay1 = sy1[ia], ax2 = sx2[ia], ay2 = sy2[ia];
        float ar2 = sarea[ia];
        bool kp = true;
        for (int b = 0; b < a; ++b) {
          if (!bucket[s0 + b]) continue;   // bucket reused as kept-flags
          int jb = sorted[s0 + b];
          float iw = fminf(ax2, sx2[jb]) - fmaxf(ax1, sx1[jb]);
          float ih = fminf(ay2, sy2[jb]) - fmaxf(ay1, sy1[jb]);
          iw = fmaxf(iw, 0.0f);
          ih = fmaxf(ih, 0.0f);
          float inter = iw * ih;
          float iou = inter / (ar2 + sarea[jb] - inter + 1e-9f);
          if (iou > NMS_TH) { kp = false; break; }
        }
        bucket[s0 + a] = kp ? 1 : 0;
        if (kp) keepOut[(size_t)n * HW + ia] = 1.0f;
      }
    }
  }
}

extern "C" void kernel_launch(void* const* d_in, const int* in_sizes, int n_in,
                              void* d_out, int out_size, void* d_ws, size_t ws_size,
                              hipStream_t stream) {
  const float* preds = (const float*)d_in[0];
  float* out = (float*)d_out;
  float* keepOut = out + (size_t)NIMG * HW * 6;

  fused_kernel<<<NIMG, HW, 0, stream>>>(preds, out, keepOut);
}